// Round 1
// baseline (630.862 us; speedup 1.0000x reference)
//
#include <hip/hip_runtime.h>
#include <hip/hip_bf16.h>
#include <math.h>

#define N_NODES_DEF 50000

__device__ __forceinline__ float lrelu02(float x) { return x > 0.f ? x : 0.2f * x; }

__device__ __forceinline__ float block_max_256(float v) {
    __shared__ float red[256];
    int t = threadIdx.x;
    red[t] = v;
    __syncthreads();
#pragma unroll
    for (int s = 128; s > 0; s >>= 1) {
        if (t < s) red[t] = fmaxf(red[t], red[t + s]);
        __syncthreads();
    }
    float r = red[0];
    __syncthreads();
    return r;
}

// ---------------- Layer-0 projection: hp0[n][h*16+o] = sum_f emb[n][f] * w0[h][f][o]
// emb = concat(dyn0[32], dyn1[32], static[64]); W staged in LDS as [f][c], c=h*16+o.
__global__ __launch_bounds__(256) void gemm0_kernel(
    const float* __restrict__ stat, const float* __restrict__ dyn0,
    const float* __restrict__ dyn1, const float* __restrict__ w0,
    float* __restrict__ hp0, int n_nodes)
{
    extern __shared__ float smem[];
    float* w_s = smem;              // 128*128
    float* emb_s = smem + 128 * 128; // 8*128
    int t = threadIdx.x;
    for (int idx = t; idx < 128 * 128; idx += 256) {
        int h = idx >> 11, f = (idx >> 4) & 127, o = idx & 15;
        w_s[f * 128 + (h << 4) + o] = w0[idx];
    }
    __syncthreads();

    int nl = t >> 5;     // node-local 0..7
    int cg = t & 31;     // column group -> columns c0..c0+3
    int c0 = cg * 4;
    int ngroups = (n_nodes + 7) >> 3;
    for (int g = blockIdx.x; g < ngroups; g += gridDim.x) {
        int base = g * 8;
        for (int i = t; i < 1024; i += 256) {
            int node = base + (i >> 7);
            int f = i & 127;
            float v = 0.f;
            if (node < n_nodes) {
                if (f < 32) v = dyn0[node * 32 + f];
                else if (f < 64) v = dyn1[node * 32 + f - 32];
                else v = stat[node * 64 + f - 64];
            }
            emb_s[i] = v;
        }
        __syncthreads();
        float a0 = 0.f, a1 = 0.f, a2 = 0.f, a3 = 0.f;
        const float* er = emb_s + nl * 128;
#pragma unroll 4
        for (int f = 0; f < 128; ++f) {
            float e = er[f];
            const float4 w4 = *reinterpret_cast<const float4*>(&w_s[f * 128 + c0]);
            a0 += e * w4.x; a1 += e * w4.y; a2 += e * w4.z; a3 += e * w4.w;
        }
        int node = base + nl;
        if (node < n_nodes) {
            float4 r; r.x = a0; r.y = a1; r.z = a2; r.w = a3;
            *reinterpret_cast<float4*>(&hp0[node * 128 + c0]) = r;
        }
        __syncthreads();
    }
}

// ---------------- per-node attention scores: s[n][h] = sum_o hp[n][h][o]*asrc[h][o]
__global__ __launch_bounds__(256) void score_kernel(
    const float* __restrict__ hp, const float* __restrict__ asrc,
    const float* __restrict__ atrg, float* __restrict__ s_out,
    float* __restrict__ t_out, int n_nodes, int H, int F)
{
    int i = blockIdx.x * blockDim.x + threadIdx.x;
    if (i >= n_nodes * H) return;
    int h = i % H;
    const float* row = hp + (size_t)i * F;
    const float* as = asrc + h * F;
    const float* at = atrg + h * F;
    float sv = 0.f, tv = 0.f;
    for (int o = 0; o < F; ++o) { float v = row[o]; sv += v * as[o]; tv += v * at[o]; }
    s_out[i] = sv; t_out[i] = tv;
}

// ---------------- global max of leaky_relu(s[src]+t[trg]) over [E, H]
__global__ __launch_bounds__(256) void edge_max_kernel(
    const int* __restrict__ src, const int* __restrict__ trg,
    const float* __restrict__ s, const float* __restrict__ t0,
    float* __restrict__ partials, int n_edges, int hshift)
{
    int H = 1 << hshift;
    long total = (long)n_edges << hshift;
    long stride = (long)gridDim.x * blockDim.x;
    float m = -INFINITY;
    for (long i = (long)blockIdx.x * blockDim.x + threadIdx.x; i < total; i += stride) {
        int e = (int)(i >> hshift);
        int h = (int)(i & (H - 1));
        float x = s[src[e] * H + h] + t0[trg[e] * H + h];
        m = fmaxf(m, lrelu02(x));
    }
    float r = block_max_256(m);
    if (threadIdx.x == 0) partials[blockIdx.x] = r;
}

__global__ __launch_bounds__(256) void max_final_kernel(
    const float* __restrict__ partials, int n, float* __restrict__ M)
{
    float m = -INFINITY;
    for (int i = threadIdx.x; i < n; i += blockDim.x) m = fmaxf(m, partials[i]);
    float r = block_max_256(m);
    if (threadIdx.x == 0) *M = r;
}

// ---------------- denom[trg][h] += exp(lrelu(s[src]+t[trg]) - M)
__global__ __launch_bounds__(256) void edge_denom_kernel(
    const int* __restrict__ src, const int* __restrict__ trg,
    const float* __restrict__ s, const float* __restrict__ t0,
    const float* __restrict__ M, float* __restrict__ denom,
    int n_edges, int hshift)
{
    int H = 1 << hshift;
    long total = (long)n_edges << hshift;
    long stride = (long)gridDim.x * blockDim.x;
    float Mv = *M;
    for (long i = (long)blockIdx.x * blockDim.x + threadIdx.x; i < total; i += stride) {
        int e = (int)(i >> hshift);
        int h = (int)(i & (H - 1));
        int te = trg[e];
        float x = s[src[e] * H + h] + t0[te * H + h];
        atomicAdd(&denom[te * H + h], expf(lrelu02(x) - Mv));
    }
}

// ---------------- out[trg][c] += hp[src][c] * alpha(e, h=c>>fshift)
__global__ __launch_bounds__(256) void edge_msg_kernel(
    const int* __restrict__ src, const int* __restrict__ trg,
    const float* __restrict__ s, const float* __restrict__ t0,
    const float* __restrict__ M, const float* __restrict__ denom,
    const float* __restrict__ hp, float* __restrict__ out,
    int n_edges, int hshift, int fshift)
{
    int H = 1 << hshift;
    int cshift = hshift + fshift;
    int C = 1 << cshift;
    long total = (long)n_edges << cshift;
    long stride = (long)gridDim.x * blockDim.x;
    float Mv = *M;
    for (long i = (long)blockIdx.x * blockDim.x + threadIdx.x; i < total; i += stride) {
        int e = (int)(i >> cshift);
        int c = (int)(i & (C - 1));
        int h = c >> fshift;
        int se = src[e], te = trg[e];
        float x = s[se * H + h] + t0[te * H + h];
        float alpha = expf(lrelu02(x) - Mv) / (denom[te * H + h] + 1e-16f);
        atomicAdd(&out[(size_t)te * C + c], hp[(size_t)se * C + c] * alpha);
    }
}

// ---------------- layer-1 prep: h1 = elu(out0); hp1 = h1 @ W1 [128x2]; s1/t1 scores
__global__ __launch_bounds__(128) void l1prep_kernel(
    const float* __restrict__ out0, const float* __restrict__ w1,
    const float* __restrict__ asrc1, const float* __restrict__ atrg1,
    float* __restrict__ hp1, float* __restrict__ s1, float* __restrict__ t1,
    int n_nodes)
{
    __shared__ float r0[128], r1[128];
    int n = blockIdx.x;
    if (n >= n_nodes) return;
    int f = threadIdx.x;
    float x = out0[(size_t)n * 128 + f];
    float v = x > 0.f ? x : expm1f(x);
    r0[f] = v * w1[f * 2 + 0];
    r1[f] = v * w1[f * 2 + 1];
    __syncthreads();
#pragma unroll
    for (int s = 64; s > 0; s >>= 1) {
        if (f < s) { r0[f] += r0[f + s]; r1[f] += r1[f + s]; }
        __syncthreads();
    }
    if (f == 0) {
        float h0 = r0[0], h1v = r1[0];
        hp1[n * 2 + 0] = h0;
        hp1[n * 2 + 1] = h1v;
        s1[n] = h0 * asrc1[0] + h1v * asrc1[1];
        t1[n] = h0 * atrg1[0] + h1v * atrg1[1];
    }
}

// ---------------- final: out[n] = log_softmax(out1[n][0..1])
__global__ __launch_bounds__(256) void logsoftmax_kernel(
    const float* __restrict__ out1, float* __restrict__ out, int n)
{
    int i = blockIdx.x * blockDim.x + threadIdx.x;
    if (i >= n) return;
    float x0 = out1[i * 2], x1 = out1[i * 2 + 1];
    float m = fmaxf(x0, x1);
    float lse = m + logf(expf(x0 - m) + expf(x1 - m));
    out[i * 2] = x0 - lse;
    out[i * 2 + 1] = x1 - lse;
}

extern "C" void kernel_launch(void* const* d_in, const int* in_sizes, int n_in,
                              void* d_out, int out_size, void* d_ws, size_t ws_size,
                              hipStream_t stream) {
    const float* stat  = (const float*)d_in[0];
    const float* dyn0  = (const float*)d_in[1];
    const float* dyn1  = (const float*)d_in[2];
    const int*   src   = (const int*)d_in[3];
    const int*   trg   = (const int*)d_in[4];
    const float* w0    = (const float*)d_in[5];
    const float* asrc0 = (const float*)d_in[6];
    const float* atrg0 = (const float*)d_in[7];
    const float* w1    = (const float*)d_in[8];
    const float* asrc1 = (const float*)d_in[9];
    const float* atrg1 = (const float*)d_in[10];
    float* out = (float*)d_out;

    const int N = in_sizes[0] / 64;   // 50000
    const int E = in_sizes[3];        // 800000

    // ---- workspace layout (floats) ----
    float* ws = (float*)d_ws;
    size_t off = 0;
    float* denom0 = ws + off; off += (size_t)N * 8;
    float* out0   = ws + off; off += (size_t)N * 128;
    float* denom1 = ws + off; off += (size_t)N;
    float* out1   = ws + off; off += (size_t)N * 2;
    size_t acc_floats = off;          // zeroed every call
    float* hp0 = ws + off; off += (size_t)N * 128;
    float* s0  = ws + off; off += (size_t)N * 8;
    float* t0  = ws + off; off += (size_t)N * 8;
    float* hp1 = ws + off; off += (size_t)N * 2;
    float* s1  = ws + off; off += (size_t)N;
    float* t1  = ws + off; off += (size_t)N;
    float* partials = ws + off; off += 1024;
    float* M0 = ws + off; off += 1;
    float* M1 = ws + off; off += 1;

    hipMemsetAsync(denom0, 0, acc_floats * sizeof(float), stream);

    // layer 0
    size_t gemm0_lds = (128 * 128 + 8 * 128) * sizeof(float);
    gemm0_kernel<<<1024, 256, gemm0_lds, stream>>>(stat, dyn0, dyn1, w0, hp0, N);
    score_kernel<<<(N * 8 + 255) / 256, 256, 0, stream>>>(hp0, asrc0, atrg0, s0, t0, N, 8, 16);
    edge_max_kernel<<<1024, 256, 0, stream>>>(src, trg, s0, t0, partials, E, 3);
    max_final_kernel<<<1, 256, 0, stream>>>(partials, 1024, M0);
    edge_denom_kernel<<<2048, 256, 0, stream>>>(src, trg, s0, t0, M0, denom0, E, 3);
    edge_msg_kernel<<<8192, 256, 0, stream>>>(src, trg, s0, t0, M0, denom0, hp0, out0, E, 3, 4);

    // layer 1
    l1prep_kernel<<<N, 128, 0, stream>>>(out0, w1, asrc1, atrg1, hp1, s1, t1, N);
    edge_max_kernel<<<1024, 256, 0, stream>>>(src, trg, s1, t1, partials, E, 0);
    max_final_kernel<<<1, 256, 0, stream>>>(partials, 1024, M1);
    edge_denom_kernel<<<1024, 256, 0, stream>>>(src, trg, s1, t1, M1, denom1, E, 0);
    edge_msg_kernel<<<1024, 256, 0, stream>>>(src, trg, s1, t1, M1, denom1, hp1, out1, E, 0, 1);

    logsoftmax_kernel<<<(N + 255) / 256, 256, 0, stream>>>(out1, out, N);
}

// Round 2
// 379.415 us; speedup vs baseline: 1.6627x; 1.6627x over previous
//
#include <hip/hip_runtime.h>
#include <hip/hip_bf16.h>
#include <math.h>

__device__ __forceinline__ float lrelu02(float x) { return x > 0.f ? x : 0.2f * x; }

#define ESHIFT 10.0f   // constant shift replacing global max (alpha is ratio-invariant)

// ---------------- CSR build ----------------
__global__ __launch_bounds__(256) void count_kernel(
    const int* __restrict__ trg, int* __restrict__ deg, int E)
{
    int i = blockIdx.x * blockDim.x + threadIdx.x;
    if (i < E) atomicAdd(&deg[trg[i]], 1);
}

__global__ __launch_bounds__(1024) void scan_kernel(
    const int* __restrict__ deg, int* __restrict__ rowptr,
    int* __restrict__ cursor, int n)
{
    __shared__ int sm[1024];
    int t = threadIdx.x;
    int C = (n + 1023) >> 10;
    int b0 = t * C, b1 = min(b0 + C, n);
    int sum = 0;
    for (int i = b0; i < b1; ++i) sum += deg[i];
    sm[t] = sum;
    __syncthreads();
    for (int off = 1; off < 1024; off <<= 1) {
        int x = (t >= off) ? sm[t - off] : 0;
        __syncthreads();
        sm[t] += x;
        __syncthreads();
    }
    int run = (t > 0) ? sm[t - 1] : 0;
    for (int i = b0; i < b1; ++i) {
        int v = deg[i];
        cursor[i] = run;
        rowptr[i + 1] = run + v;
        run += v;
    }
    if (t == 0) rowptr[0] = 0;
}

__global__ __launch_bounds__(256) void scatter_kernel(
    const int* __restrict__ src, const int* __restrict__ trg,
    int* __restrict__ cursor, int* __restrict__ colsrc, int E)
{
    int i = blockIdx.x * blockDim.x + threadIdx.x;
    if (i < E) {
        int pos = atomicAdd(&cursor[trg[i]], 1);
        colsrc[pos] = src[i];
    }
}

// ---------------- Layer-0 projection + fused s0/t0 scores ----------------
// hp0[n][h*16+o] = sum_f emb[n][f] * w0[h][f][o];  emb = [dyn0|dyn1|static]
__global__ __launch_bounds__(256) void gemm0_kernel(
    const float* __restrict__ stat, const float* __restrict__ dyn0,
    const float* __restrict__ dyn1, const float* __restrict__ w0,
    const float* __restrict__ asrc0, const float* __restrict__ atrg0,
    float* __restrict__ hp0, float* __restrict__ s0, float* __restrict__ t0,
    int n_nodes)
{
    extern __shared__ float smem[];
    float* w_s = smem;               // 128*128, layout [f][c], c = h*16+o
    float* emb_s = smem + 128 * 128; // 8*128
    int t = threadIdx.x;
    for (int idx = t; idx < 128 * 128; idx += 256) {
        int h = idx >> 11, f = (idx >> 4) & 127, o = idx & 15;
        w_s[f * 128 + (h << 4) + o] = w0[idx];
    }
    __syncthreads();

    int nl = t >> 5;     // node-local 0..7
    int cg = t & 31;     // column group -> channels c0..c0+3
    int c0 = cg * 4;
    int h = c0 >> 4;
    int o0 = c0 & 15;
    // attention weight slices for my 4 channels (loop-invariant)
    float as0 = asrc0[h * 16 + o0], as1 = asrc0[h * 16 + o0 + 1];
    float as2 = asrc0[h * 16 + o0 + 2], as3 = asrc0[h * 16 + o0 + 3];
    float at0 = atrg0[h * 16 + o0], at1 = atrg0[h * 16 + o0 + 1];
    float at2 = atrg0[h * 16 + o0 + 2], at3 = atrg0[h * 16 + o0 + 3];

    int ngroups = (n_nodes + 7) >> 3;
    for (int g = blockIdx.x; g < ngroups; g += gridDim.x) {
        int base = g * 8;
        for (int i = t; i < 1024; i += 256) {
            int node = base + (i >> 7);
            int f = i & 127;
            float v = 0.f;
            if (node < n_nodes) {
                if (f < 32) v = dyn0[node * 32 + f];
                else if (f < 64) v = dyn1[node * 32 + f - 32];
                else v = stat[node * 64 + f - 64];
            }
            emb_s[i] = v;
        }
        __syncthreads();
        float a0 = 0.f, a1 = 0.f, a2 = 0.f, a3 = 0.f;
        const float* er = emb_s + nl * 128;
#pragma unroll 4
        for (int f = 0; f < 128; ++f) {
            float e = er[f];
            const float4 w4 = *reinterpret_cast<const float4*>(&w_s[f * 128 + c0]);
            a0 += e * w4.x; a1 += e * w4.y; a2 += e * w4.z; a3 += e * w4.w;
        }
        int node = base + nl;
        if (node < n_nodes) {
            float4 r; r.x = a0; r.y = a1; r.z = a2; r.w = a3;
            *reinterpret_cast<float4*>(&hp0[(size_t)node * 128 + c0]) = r;
        }
        // fused per-head scores: reduce over the 4 lanes sharing head h
        float ps = a0 * as0 + a1 * as1 + a2 * as2 + a3 * as3;
        float pt = a0 * at0 + a1 * at1 + a2 * at2 + a3 * at3;
        ps += __shfl_xor(ps, 1); ps += __shfl_xor(ps, 2);
        pt += __shfl_xor(pt, 1); pt += __shfl_xor(pt, 2);
        if ((cg & 3) == 0 && node < n_nodes) {
            s0[node * 8 + h] = ps;
            t0[node * 8 + h] = pt;
        }
        __syncthreads();
    }
}

// ---------------- Layer-0 per-target-node accumulate (denom+msg one pass)
// + fused ELU + W1 projection + layer-1 scores.
#define CH0 64
__global__ __launch_bounds__(128) void node_accum0_kernel(
    const int* __restrict__ rowptr, const int* __restrict__ colsrc,
    const float* __restrict__ s0, const float* __restrict__ t0,
    const float* __restrict__ hp0, const float* __restrict__ w1,
    const float* __restrict__ asrc1, const float* __restrict__ atrg1,
    float* __restrict__ hp1, float* __restrict__ s1, float* __restrict__ t1,
    int n_nodes)
{
    __shared__ int   se_s[CH0];
    __shared__ float p_s[CH0 * 8];
    __shared__ float denom_s[8];
    __shared__ float t_row[8];
    __shared__ float red0[128], red1[128];

    int n = blockIdx.x;
    int t = threadIdx.x;
    int h = t >> 4;
    int start = rowptr[n];
    int deg = rowptr[n + 1] - start;

    if (t < 8) { t_row[t] = t0[n * 8 + t]; denom_s[t] = 0.f; }
    __syncthreads();

    float acc = 0.f;
    for (int chunk = 0; chunk < deg; chunk += CH0) {
        int m = min(CH0, deg - chunk);
        if (t < m) se_s[t] = colsrc[start + chunk + t];
        __syncthreads();
        for (int j = t; j < m * 8; j += 128) {
            int e = j >> 3, hh = j & 7;
            float x = s0[se_s[e] * 8 + hh] + t_row[hh];
            float p = __expf(lrelu02(x) - ESHIFT);
            p_s[j] = p;
            atomicAdd(&denom_s[hh], p);
        }
        __syncthreads();
        for (int e = 0; e < m; ++e)
            acc += hp0[(size_t)se_s[e] * 128 + t] * p_s[e * 8 + h];
        __syncthreads();
    }

    float v = acc / (denom_s[h] + 1e-16f);
    // ELU
    v = v > 0.f ? v : expm1f(v);
    // W1 projection: hp1[n][j] = sum_c v_c * w1[c*2+j]
    red0[t] = v * w1[t * 2 + 0];
    red1[t] = v * w1[t * 2 + 1];
    __syncthreads();
#pragma unroll
    for (int s = 64; s > 0; s >>= 1) {
        if (t < s) { red0[t] += red0[t + s]; red1[t] += red1[t + s]; }
        __syncthreads();
    }
    if (t == 0) {
        float h0 = red0[0], h1v = red1[0];
        hp1[n * 2 + 0] = h0;
        hp1[n * 2 + 1] = h1v;
        s1[n] = h0 * asrc1[0] + h1v * asrc1[1];
        t1[n] = h0 * atrg1[0] + h1v * atrg1[1];
    }
}

// ---------------- Layer-1 per-node accumulate + mean + log_softmax -> out
__global__ __launch_bounds__(256) void node_accum1_kernel(
    const int* __restrict__ rowptr, const int* __restrict__ colsrc,
    const float* __restrict__ s1, const float* __restrict__ t1,
    const float* __restrict__ hp1, float* __restrict__ out, int n_nodes)
{
    int lane = threadIdx.x & 63;
    int n = blockIdx.x * 4 + (threadIdx.x >> 6);
    if (n >= n_nodes) return;
    int start = rowptr[n], deg = rowptr[n + 1] - start;
    float tn = t1[n];
    float d = 0.f, a0 = 0.f, a1 = 0.f;
    for (int i = lane; i < deg; i += 64) {
        int se = colsrc[start + i];
        float p = __expf(lrelu02(s1[se] + tn) - ESHIFT);
        d += p;
        a0 += p * hp1[se * 2 + 0];
        a1 += p * hp1[se * 2 + 1];
    }
#pragma unroll
    for (int off = 32; off > 0; off >>= 1) {
        d  += __shfl_down(d, off);
        a0 += __shfl_down(a0, off);
        a1 += __shfl_down(a1, off);
    }
    if (lane == 0) {
        float inv = 1.f / (d + 1e-16f);
        float x0 = a0 * inv, x1 = a1 * inv;
        float m = fmaxf(x0, x1);
        float lse = m + logf(__expf(x0 - m) + __expf(x1 - m));
        out[n * 2 + 0] = x0 - lse;
        out[n * 2 + 1] = x1 - lse;
    }
}

extern "C" void kernel_launch(void* const* d_in, const int* in_sizes, int n_in,
                              void* d_out, int out_size, void* d_ws, size_t ws_size,
                              hipStream_t stream) {
    const float* stat  = (const float*)d_in[0];
    const float* dyn0  = (const float*)d_in[1];
    const float* dyn1  = (const float*)d_in[2];
    const int*   src   = (const int*)d_in[3];
    const int*   trg   = (const int*)d_in[4];
    const float* w0    = (const float*)d_in[5];
    const float* asrc0 = (const float*)d_in[6];
    const float* atrg0 = (const float*)d_in[7];
    const float* w1    = (const float*)d_in[8];
    const float* asrc1 = (const float*)d_in[9];
    const float* atrg1 = (const float*)d_in[10];
    float* out = (float*)d_out;

    const int N = in_sizes[0] / 64;   // 50000
    const int E = in_sizes[3];        // 800000

    // ---- workspace layout ----
    float* ws = (float*)d_ws;
    size_t off = 0;
    float* hp0 = ws + off; off += (size_t)N * 128;
    float* s0  = ws + off; off += (size_t)N * 8;
    float* t0  = ws + off; off += (size_t)N * 8;
    float* hp1 = ws + off; off += (size_t)N * 2;
    float* s1  = ws + off; off += (size_t)N;
    float* t1  = ws + off; off += (size_t)N;
    int* iws    = (int*)(ws + off);
    int* rowptr = iws;               // N+1
    int* cursor = iws + (N + 1);     // N
    int* colsrc = iws + (N + 1) + N; // E
    int* deg    = colsrc + E;        // N

    // CSR build (by target)
    hipMemsetAsync(deg, 0, (size_t)N * sizeof(int), stream);
    count_kernel<<<(E + 255) / 256, 256, 0, stream>>>(trg, deg, E);
    scan_kernel<<<1, 1024, 0, stream>>>(deg, rowptr, cursor, N);
    scatter_kernel<<<(E + 255) / 256, 256, 0, stream>>>(src, trg, cursor, colsrc, E);

    // layer 0 projection + scores
    size_t gemm0_lds = (128 * 128 + 8 * 128) * sizeof(float);
    gemm0_kernel<<<1024, 256, gemm0_lds, stream>>>(
        stat, dyn0, dyn1, w0, asrc0, atrg0, hp0, s0, t0, N);

    // layer 0 aggregate + ELU + W1 + layer-1 scores
    node_accum0_kernel<<<N, 128, 0, stream>>>(
        rowptr, colsrc, s0, t0, hp0, w1, asrc1, atrg1, hp1, s1, t1, N);

    // layer 1 aggregate + mean + log_softmax
    node_accum1_kernel<<<(N + 3) / 4, 256, 0, stream>>>(
        rowptr, colsrc, s1, t1, hp1, out, N);
}

// Round 3
// 279.356 us; speedup vs baseline: 2.2583x; 1.3582x over previous
//
#include <hip/hip_runtime.h>
#include <hip/hip_bf16.h>
#include <math.h>

__device__ __forceinline__ float lrelu02(float x) { return x > 0.f ? x : 0.2f * x; }

#define ESHIFT 10.0f   // constant shift replacing global max (alpha is ratio-invariant)

// ---------------- CSR build ----------------
__global__ __launch_bounds__(256) void count_kernel(
    const int* __restrict__ trg, int* __restrict__ deg, int E)
{
    int i = blockIdx.x * blockDim.x + threadIdx.x;
    if (i < E) atomicAdd(&deg[trg[i]], 1);
}

// Stage A: per-block (256 elems) sum of deg
__global__ __launch_bounds__(256) void block_sum_kernel(
    const int* __restrict__ deg, int* __restrict__ bsum, int n)
{
    __shared__ int sm[256];
    int t = threadIdx.x;
    int i = blockIdx.x * 256 + t;
    sm[t] = (i < n) ? deg[i] : 0;
    __syncthreads();
#pragma unroll
    for (int s = 128; s > 0; s >>= 1) {
        if (t < s) sm[t] += sm[t + s];
        __syncthreads();
    }
    if (t == 0) bsum[blockIdx.x] = sm[0];
}

// Stage B: exclusive scan of block sums (nb <= 1024), in place
__global__ __launch_bounds__(1024) void bsum_scan_kernel(
    int* __restrict__ bsum, int nb)
{
    __shared__ int sm[1024];
    int t = threadIdx.x;
    sm[t] = (t < nb) ? bsum[t] : 0;
    __syncthreads();
    for (int off = 1; off < 1024; off <<= 1) {
        int x = (t >= off) ? sm[t - off] : 0;
        __syncthreads();
        sm[t] += x;
        __syncthreads();
    }
    if (t < nb) bsum[t] = (t > 0) ? sm[t - 1] : 0;
}

// Stage C: per-block inclusive scan + global offset -> rowptr, cursor
__global__ __launch_bounds__(256) void scan_write_kernel(
    const int* __restrict__ deg, const int* __restrict__ bsum,
    int* __restrict__ rowptr, int* __restrict__ cursor, int n)
{
    __shared__ int sm[256];
    int t = threadIdx.x;
    int i = blockIdx.x * 256 + t;
    int v = (i < n) ? deg[i] : 0;
    sm[t] = v;
    __syncthreads();
    for (int off = 1; off < 256; off <<= 1) {
        int x = (t >= off) ? sm[t - off] : 0;
        __syncthreads();
        sm[t] += x;
        __syncthreads();
    }
    int incl = sm[t];
    int base = bsum[blockIdx.x];
    if (i < n) {
        cursor[i] = base + incl - v;
        rowptr[i + 1] = base + incl;
    }
    if (i == 0) rowptr[0] = 0;
}

__global__ __launch_bounds__(256) void scatter_kernel(
    const int* __restrict__ src, const int* __restrict__ trg,
    int* __restrict__ cursor, int* __restrict__ colsrc, int E)
{
    int i = blockIdx.x * blockDim.x + threadIdx.x;
    if (i < E) {
        int pos = atomicAdd(&cursor[trg[i]], 1);
        colsrc[pos] = src[i];
    }
}

// ---------------- Layer-0 projection + fused s0/t0 scores ----------------
// hp0[n][h*16+o] = sum_f emb[n][f] * w0[h][f][o];  emb = [dyn0|dyn1|static]
__global__ __launch_bounds__(256) void gemm0_kernel(
    const float* __restrict__ stat, const float* __restrict__ dyn0,
    const float* __restrict__ dyn1, const float* __restrict__ w0,
    const float* __restrict__ asrc0, const float* __restrict__ atrg0,
    float* __restrict__ hp0, float* __restrict__ s0, float* __restrict__ t0,
    int n_nodes)
{
    extern __shared__ float smem[];
    float* w_s = smem;               // 128*128, layout [f][c], c = h*16+o
    float* emb_s = smem + 128 * 128; // 8*128
    int t = threadIdx.x;
    for (int idx = t; idx < 128 * 128; idx += 256) {
        int h = idx >> 11, f = (idx >> 4) & 127, o = idx & 15;
        w_s[f * 128 + (h << 4) + o] = w0[idx];
    }
    __syncthreads();

    int nl = t >> 5;     // node-local 0..7
    int cg = t & 31;     // column group -> channels c0..c0+3
    int c0 = cg * 4;
    int h = c0 >> 4;
    int o0 = c0 & 15;
    float as0 = asrc0[h * 16 + o0], as1 = asrc0[h * 16 + o0 + 1];
    float as2 = asrc0[h * 16 + o0 + 2], as3 = asrc0[h * 16 + o0 + 3];
    float at0 = atrg0[h * 16 + o0], at1 = atrg0[h * 16 + o0 + 1];
    float at2 = atrg0[h * 16 + o0 + 2], at3 = atrg0[h * 16 + o0 + 3];

    int ngroups = (n_nodes + 7) >> 3;
    for (int g = blockIdx.x; g < ngroups; g += gridDim.x) {
        int base = g * 8;
        for (int i = t; i < 1024; i += 256) {
            int node = base + (i >> 7);
            int f = i & 127;
            float v = 0.f;
            if (node < n_nodes) {
                if (f < 32) v = dyn0[node * 32 + f];
                else if (f < 64) v = dyn1[node * 32 + f - 32];
                else v = stat[node * 64 + f - 64];
            }
            emb_s[i] = v;
        }
        __syncthreads();
        float a0 = 0.f, a1 = 0.f, a2 = 0.f, a3 = 0.f;
        const float* er = emb_s + nl * 128;
#pragma unroll 4
        for (int f = 0; f < 128; ++f) {
            float e = er[f];
            const float4 w4 = *reinterpret_cast<const float4*>(&w_s[f * 128 + c0]);
            a0 += e * w4.x; a1 += e * w4.y; a2 += e * w4.z; a3 += e * w4.w;
        }
        int node = base + nl;
        if (node < n_nodes) {
            float4 r; r.x = a0; r.y = a1; r.z = a2; r.w = a3;
            *reinterpret_cast<float4*>(&hp0[(size_t)node * 128 + c0]) = r;
        }
        float ps = a0 * as0 + a1 * as1 + a2 * as2 + a3 * as3;
        float pt = a0 * at0 + a1 * at1 + a2 * at2 + a3 * at3;
        ps += __shfl_xor(ps, 1); ps += __shfl_xor(ps, 2);
        pt += __shfl_xor(pt, 1); pt += __shfl_xor(pt, 2);
        if ((cg & 3) == 0 && node < n_nodes) {
            s0[node * 8 + h] = ps;
            t0[node * 8 + h] = pt;
        }
        __syncthreads();
    }
}

// ---------------- Layer-0 per-target-node accumulate (denom+msg one pass)
// + fused ELU + W1 projection + layer-1 scores.
#define CH0 64
__global__ __launch_bounds__(128) void node_accum0_kernel(
    const int* __restrict__ rowptr, const int* __restrict__ colsrc,
    const float* __restrict__ s0, const float* __restrict__ t0,
    const float* __restrict__ hp0, const float* __restrict__ w1,
    const float* __restrict__ asrc1, const float* __restrict__ atrg1,
    float* __restrict__ hp1, float* __restrict__ s1, float* __restrict__ t1,
    int n_nodes)
{
    __shared__ int   se_s[CH0];
    __shared__ float p_s[CH0 * 8];
    __shared__ float denom_s[8];
    __shared__ float t_row[8];
    __shared__ float red0[128], red1[128];

    int n = blockIdx.x;
    int t = threadIdx.x;
    int h = t >> 4;
    int start = rowptr[n];
    int deg = rowptr[n + 1] - start;

    if (t < 8) { t_row[t] = t0[n * 8 + t]; denom_s[t] = 0.f; }
    __syncthreads();

    float acc = 0.f;
    for (int chunk = 0; chunk < deg; chunk += CH0) {
        int m = min(CH0, deg - chunk);
        if (t < m) se_s[t] = colsrc[start + chunk + t];
        __syncthreads();
        for (int j = t; j < m * 8; j += 128) {
            int e = j >> 3, hh = j & 7;
            float x = s0[se_s[e] * 8 + hh] + t_row[hh];
            float p = __expf(lrelu02(x) - ESHIFT);
            p_s[j] = p;
            atomicAdd(&denom_s[hh], p);
        }
        __syncthreads();
        for (int e = 0; e < m; ++e)
            acc += hp0[(size_t)se_s[e] * 128 + t] * p_s[e * 8 + h];
        __syncthreads();
    }

    float v = acc / (denom_s[h] + 1e-16f);
    v = v > 0.f ? v : expm1f(v);
    red0[t] = v * w1[t * 2 + 0];
    red1[t] = v * w1[t * 2 + 1];
    __syncthreads();
#pragma unroll
    for (int s = 64; s > 0; s >>= 1) {
        if (t < s) { red0[t] += red0[t + s]; red1[t] += red1[t + s]; }
        __syncthreads();
    }
    if (t == 0) {
        float h0 = red0[0], h1v = red1[0];
        hp1[n * 2 + 0] = h0;
        hp1[n * 2 + 1] = h1v;
        s1[n] = h0 * asrc1[0] + h1v * asrc1[1];
        t1[n] = h0 * atrg1[0] + h1v * atrg1[1];
    }
}

// ---------------- Layer-1 per-node accumulate + mean + log_softmax -> out
__global__ __launch_bounds__(256) void node_accum1_kernel(
    const int* __restrict__ rowptr, const int* __restrict__ colsrc,
    const float* __restrict__ s1, const float* __restrict__ t1,
    const float* __restrict__ hp1, float* __restrict__ out, int n_nodes)
{
    int lane = threadIdx.x & 63;
    int n = blockIdx.x * 4 + (threadIdx.x >> 6);
    if (n >= n_nodes) return;
    int start = rowptr[n], deg = rowptr[n + 1] - start;
    float tn = t1[n];
    float d = 0.f, a0 = 0.f, a1 = 0.f;
    for (int i = lane; i < deg; i += 64) {
        int se = colsrc[start + i];
        float p = __expf(lrelu02(s1[se] + tn) - ESHIFT);
        d += p;
        a0 += p * hp1[se * 2 + 0];
        a1 += p * hp1[se * 2 + 1];
    }
#pragma unroll
    for (int off = 32; off > 0; off >>= 1) {
        d  += __shfl_down(d, off);
        a0 += __shfl_down(a0, off);
        a1 += __shfl_down(a1, off);
    }
    if (lane == 0) {
        float inv = 1.f / (d + 1e-16f);
        float x0 = a0 * inv, x1 = a1 * inv;
        float m = fmaxf(x0, x1);
        float lse = m + logf(__expf(x0 - m) + __expf(x1 - m));
        out[n * 2 + 0] = x0 - lse;
        out[n * 2 + 1] = x1 - lse;
    }
}

extern "C" void kernel_launch(void* const* d_in, const int* in_sizes, int n_in,
                              void* d_out, int out_size, void* d_ws, size_t ws_size,
                              hipStream_t stream) {
    const float* stat  = (const float*)d_in[0];
    const float* dyn0  = (const float*)d_in[1];
    const float* dyn1  = (const float*)d_in[2];
    const int*   src   = (const int*)d_in[3];
    const int*   trg   = (const int*)d_in[4];
    const float* w0    = (const float*)d_in[5];
    const float* asrc0 = (const float*)d_in[6];
    const float* atrg0 = (const float*)d_in[7];
    const float* w1    = (const float*)d_in[8];
    const float* asrc1 = (const float*)d_in[9];
    const float* atrg1 = (const float*)d_in[10];
    float* out = (float*)d_out;

    const int N = in_sizes[0] / 64;   // 50000
    const int E = in_sizes[3];        // 800000

    // ---- workspace layout ----
    float* ws = (float*)d_ws;
    size_t off = 0;
    float* hp0 = ws + off; off += (size_t)N * 128;
    float* s0  = ws + off; off += (size_t)N * 8;
    float* t0  = ws + off; off += (size_t)N * 8;
    float* hp1 = ws + off; off += (size_t)N * 2;
    float* s1  = ws + off; off += (size_t)N;
    float* t1  = ws + off; off += (size_t)N;
    int* iws    = (int*)(ws + off);
    int* rowptr = iws;               // N+1
    int* cursor = iws + (N + 1);     // N
    int* colsrc = iws + (N + 1) + N; // E
    int* deg    = colsrc + E;        // N
    int* bsum   = deg + N;           // <=1024

    const int NB = (N + 255) / 256;  // scan blocks (196 for N=50000)

    // CSR build (by target)
    hipMemsetAsync(deg, 0, (size_t)N * sizeof(int), stream);
    count_kernel<<<(E + 255) / 256, 256, 0, stream>>>(trg, deg, E);
    block_sum_kernel<<<NB, 256, 0, stream>>>(deg, bsum, N);
    bsum_scan_kernel<<<1, 1024, 0, stream>>>(bsum, NB);
    scan_write_kernel<<<NB, 256, 0, stream>>>(deg, bsum, rowptr, cursor, N);
    scatter_kernel<<<(E + 255) / 256, 256, 0, stream>>>(src, trg, cursor, colsrc, E);

    // layer 0 projection + scores
    size_t gemm0_lds = (128 * 128 + 8 * 128) * sizeof(float);
    gemm0_kernel<<<1024, 256, gemm0_lds, stream>>>(
        stat, dyn0, dyn1, w0, asrc0, atrg0, hp0, s0, t0, N);

    // layer 0 aggregate + ELU + W1 + layer-1 scores
    node_accum0_kernel<<<N, 128, 0, stream>>>(
        rowptr, colsrc, s0, t0, hp0, w1, asrc1, atrg1, hp1, s1, t1, N);

    // layer 1 aggregate + mean + log_softmax
    node_accum1_kernel<<<(N + 3) / 4, 256, 0, stream>>>(
        rowptr, colsrc, s1, t1, hp1, out, N);
}

// Round 4
// 207.037 us; speedup vs baseline: 3.0471x; 1.3493x over previous
//
#include <hip/hip_runtime.h>
#include <hip/hip_fp16.h>
#include <math.h>

__device__ __forceinline__ float lrelu02(float x) { return x > 0.f ? x : 0.2f * x; }

#define ESHIFT 10.0f   // constant shift replacing global max (alpha is ratio-invariant)

// ---------------- CSR build ----------------
__global__ __launch_bounds__(256) void count_kernel(
    const int* __restrict__ trg, int* __restrict__ deg, int E)
{
    int i = blockIdx.x * blockDim.x + threadIdx.x;
    if (i < E) atomicAdd(&deg[trg[i]], 1);
}

__global__ __launch_bounds__(256) void block_sum_kernel(
    const int* __restrict__ deg, int* __restrict__ bsum, int n)
{
    __shared__ int sm[256];
    int t = threadIdx.x;
    int i = blockIdx.x * 256 + t;
    sm[t] = (i < n) ? deg[i] : 0;
    __syncthreads();
#pragma unroll
    for (int s = 128; s > 0; s >>= 1) {
        if (t < s) sm[t] += sm[t + s];
        __syncthreads();
    }
    if (t == 0) bsum[blockIdx.x] = sm[0];
}

__global__ __launch_bounds__(1024) void bsum_scan_kernel(
    int* __restrict__ bsum, int nb)
{
    __shared__ int sm[1024];
    int t = threadIdx.x;
    sm[t] = (t < nb) ? bsum[t] : 0;
    __syncthreads();
    for (int off = 1; off < 1024; off <<= 1) {
        int x = (t >= off) ? sm[t - off] : 0;
        __syncthreads();
        sm[t] += x;
        __syncthreads();
    }
    if (t < nb) bsum[t] = (t > 0) ? sm[t - 1] : 0;
}

__global__ __launch_bounds__(256) void scan_write_kernel(
    const int* __restrict__ deg, const int* __restrict__ bsum,
    int* __restrict__ rowptr, int* __restrict__ cursor, int n)
{
    __shared__ int sm[256];
    int t = threadIdx.x;
    int i = blockIdx.x * 256 + t;
    int v = (i < n) ? deg[i] : 0;
    sm[t] = v;
    __syncthreads();
    for (int off = 1; off < 256; off <<= 1) {
        int x = (t >= off) ? sm[t - off] : 0;
        __syncthreads();
        sm[t] += x;
        __syncthreads();
    }
    int incl = sm[t];
    int base = bsum[blockIdx.x];
    if (i < n) {
        cursor[i] = base + incl - v;
        rowptr[i + 1] = base + incl;
    }
    if (i == 0) rowptr[0] = 0;
}

__global__ __launch_bounds__(256) void scatter_kernel(
    const int* __restrict__ src, const int* __restrict__ trg,
    int* __restrict__ cursor, int* __restrict__ colsrc, int E)
{
    int i = blockIdx.x * blockDim.x + threadIdx.x;
    if (i < E) {
        int pos = atomicAdd(&cursor[trg[i]], 1);
        colsrc[pos] = src[i];
    }
}

#define LOAD4(dst, ptr) { float4 _v = *reinterpret_cast<const float4*>(ptr); \
                          dst[0]=_v.x; dst[1]=_v.y; dst[2]=_v.z; dst[3]=_v.w; }

// ---------------- Layer-0 projection (4 nodes x 4 ch per thread) ----------------
// hp0h[n][c/2] = half2(hp[n][c], hp[n][c+1]);  also s0/t0 scores.
__global__ __launch_bounds__(256) void gemm0_kernel(
    const float* __restrict__ stat, const float* __restrict__ dyn0,
    const float* __restrict__ dyn1, const float* __restrict__ w0,
    const float* __restrict__ asrc0, const float* __restrict__ atrg0,
    __half2* __restrict__ hp0h, float* __restrict__ s0, float* __restrict__ t0,
    int n_nodes)
{
    __shared__ float w_s[128 * 128];   // [f][c], c = h*16+o
    int t = threadIdx.x;
    for (int i = t; i < 4096; i += 256) {
        int idx = i * 4;
        int h = idx >> 11, f = (idx >> 4) & 127, o = idx & 15;
        float4 v = *reinterpret_cast<const float4*>(&w0[idx]);
        *reinterpret_cast<float4*>(&w_s[f * 128 + h * 16 + o]) = v;
    }
    __syncthreads();

    int cg = t & 31, ns = t >> 5;
    int c0 = cg * 4;
    int h = c0 >> 4, o0 = c0 & 15;
    float4 asv = *reinterpret_cast<const float4*>(&asrc0[h * 16 + o0]);
    float4 atv = *reinterpret_cast<const float4*>(&atrg0[h * 16 + o0]);

    int ntiles = (n_nodes + 31) >> 5;
    for (int tile = blockIdx.x; tile < ntiles; tile += gridDim.x) {
        int nb = tile * 32 + ns * 4;
        int nn[4] = { nb, nb + 1, nb + 2, nb + 3 };
        int nc[4];
#pragma unroll
        for (int i = 0; i < 4; ++i) nc[i] = min(nn[i], n_nodes - 1);

        float acc[4][4];
#pragma unroll
        for (int i = 0; i < 4; ++i)
#pragma unroll
            for (int j = 0; j < 4; ++j) acc[i][j] = 0.f;

        // f in [0,32): dyn0
#pragma unroll 2
        for (int fq = 0; fq < 8; ++fq) {
            float e0[4], e1[4], e2[4], e3[4];
            LOAD4(e0, &dyn0[(size_t)nc[0] * 32 + fq * 4]);
            LOAD4(e1, &dyn0[(size_t)nc[1] * 32 + fq * 4]);
            LOAD4(e2, &dyn0[(size_t)nc[2] * 32 + fq * 4]);
            LOAD4(e3, &dyn0[(size_t)nc[3] * 32 + fq * 4]);
#pragma unroll
            for (int k = 0; k < 4; ++k) {
                float wk[4];
                LOAD4(wk, &w_s[(fq * 4 + k) * 128 + c0]);
#pragma unroll
                for (int j = 0; j < 4; ++j) {
                    acc[0][j] += e0[k] * wk[j];
                    acc[1][j] += e1[k] * wk[j];
                    acc[2][j] += e2[k] * wk[j];
                    acc[3][j] += e3[k] * wk[j];
                }
            }
        }
        // f in [32,64): dyn1
#pragma unroll 2
        for (int fq = 0; fq < 8; ++fq) {
            float e0[4], e1[4], e2[4], e3[4];
            LOAD4(e0, &dyn1[(size_t)nc[0] * 32 + fq * 4]);
            LOAD4(e1, &dyn1[(size_t)nc[1] * 32 + fq * 4]);
            LOAD4(e2, &dyn1[(size_t)nc[2] * 32 + fq * 4]);
            LOAD4(e3, &dyn1[(size_t)nc[3] * 32 + fq * 4]);
#pragma unroll
            for (int k = 0; k < 4; ++k) {
                float wk[4];
                LOAD4(wk, &w_s[(32 + fq * 4 + k) * 128 + c0]);
#pragma unroll
                for (int j = 0; j < 4; ++j) {
                    acc[0][j] += e0[k] * wk[j];
                    acc[1][j] += e1[k] * wk[j];
                    acc[2][j] += e2[k] * wk[j];
                    acc[3][j] += e3[k] * wk[j];
                }
            }
        }
        // f in [64,128): stat
#pragma unroll 2
        for (int fq = 0; fq < 16; ++fq) {
            float e0[4], e1[4], e2[4], e3[4];
            LOAD4(e0, &stat[(size_t)nc[0] * 64 + fq * 4]);
            LOAD4(e1, &stat[(size_t)nc[1] * 64 + fq * 4]);
            LOAD4(e2, &stat[(size_t)nc[2] * 64 + fq * 4]);
            LOAD4(e3, &stat[(size_t)nc[3] * 64 + fq * 4]);
#pragma unroll
            for (int k = 0; k < 4; ++k) {
                float wk[4];
                LOAD4(wk, &w_s[(64 + fq * 4 + k) * 128 + c0]);
#pragma unroll
                for (int j = 0; j < 4; ++j) {
                    acc[0][j] += e0[k] * wk[j];
                    acc[1][j] += e1[k] * wk[j];
                    acc[2][j] += e2[k] * wk[j];
                    acc[3][j] += e3[k] * wk[j];
                }
            }
        }

#pragma unroll
        for (int i = 0; i < 4; ++i) {
            bool valid = nn[i] < n_nodes;
            if (valid) {
                hp0h[(size_t)nn[i] * 64 + (c0 >> 1)]     = __floats2half2_rn(acc[i][0], acc[i][1]);
                hp0h[(size_t)nn[i] * 64 + (c0 >> 1) + 1] = __floats2half2_rn(acc[i][2], acc[i][3]);
            }
            float ps = acc[i][0] * asv.x + acc[i][1] * asv.y + acc[i][2] * asv.z + acc[i][3] * asv.w;
            float pt = acc[i][0] * atv.x + acc[i][1] * atv.y + acc[i][2] * atv.z + acc[i][3] * atv.w;
            ps += __shfl_xor(ps, 1); ps += __shfl_xor(ps, 2);
            pt += __shfl_xor(pt, 1); pt += __shfl_xor(pt, 2);
            if ((cg & 3) == 0 && valid) {
                s0[nn[i] * 8 + h] = ps;
                t0[nn[i] * 8 + h] = pt;
            }
        }
    }
}

// ---------------- Layer-0 aggregate: one WAVE per target node ----------------
// lane l owns channels 2l,2l+1 (head hc=l>>3); also computes p for head hl=l&7.
// Fused: denom+msg one pass, ELU, W1 proj, layer-1 scores -> pk1={h0,h1,s1,_}, t1.
#define CH 64
__global__ __launch_bounds__(256) void node_accum0_kernel(
    const int* __restrict__ rowptr, const int* __restrict__ colsrc,
    const float* __restrict__ s0, const float* __restrict__ t0,
    const __half2* __restrict__ hp0h, const float* __restrict__ w1,
    const float* __restrict__ asrc1, const float* __restrict__ atrg1,
    float4* __restrict__ pk1, float* __restrict__ t1, int n_nodes)
{
    __shared__ int   se_s[4][CH];
    __shared__ float p_s[4][CH * 8];

    int w = threadIdx.x >> 6;
    int l = threadIdx.x & 63;
    int n = blockIdx.x * 4 + w;
    if (n >= n_nodes) return;

    int start = rowptr[n];
    int deg = rowptr[n + 1] - start;
    int hl = l & 7;          // head for p-compute
    int hc = l >> 3;         // head of my channels
    float tval = t0[n * 8 + hl];
    const float* pw = p_s[w];

    float acc0 = 0.f, acc1 = 0.f, dsum = 0.f;
    for (int chunk = 0; chunk < deg; chunk += CH) {
        int m = min(CH, deg - chunk);
        if (l < m) se_s[w][l] = colsrc[start + chunk + l];
        __builtin_amdgcn_wave_barrier();
        int iters = (m + 7) >> 3;
        for (int r = 0; r < iters; ++r) {
            int e = r * 8 + (l >> 3);
            float p = 0.f;
            if (e < m) {
                int se = se_s[w][e];
                float x = s0[se * 8 + hl] + tval;
                p = __expf(lrelu02(x) - ESHIFT);
            }
            p_s[w][r * 64 + l] = p;   // == p_s[e*8 + hl]
            dsum += p;
        }
        __builtin_amdgcn_wave_barrier();
        int e = 0;
        for (; e + 4 <= m; e += 4) {
            int sa = se_s[w][e + 0], sb = se_s[w][e + 1];
            int sc = se_s[w][e + 2], sd = se_s[w][e + 3];
            float2 fa = __half22float2(hp0h[(size_t)sa * 64 + l]);
            float2 fb = __half22float2(hp0h[(size_t)sb * 64 + l]);
            float2 fc = __half22float2(hp0h[(size_t)sc * 64 + l]);
            float2 fd = __half22float2(hp0h[(size_t)sd * 64 + l]);
            float pa = pw[(e + 0) * 8 + hc], pb = pw[(e + 1) * 8 + hc];
            float pc2 = pw[(e + 2) * 8 + hc], pd = pw[(e + 3) * 8 + hc];
            acc0 += fa.x * pa; acc1 += fa.y * pa;
            acc0 += fb.x * pb; acc1 += fb.y * pb;
            acc0 += fc.x * pc2; acc1 += fc.y * pc2;
            acc0 += fd.x * pd; acc1 += fd.y * pd;
        }
        for (; e < m; ++e) {
            int sa = se_s[w][e];
            float2 fa = __half22float2(hp0h[(size_t)sa * 64 + l]);
            float pa = pw[e * 8 + hc];
            acc0 += fa.x * pa; acc1 += fa.y * pa;
        }
        __builtin_amdgcn_wave_barrier();
    }

    // denom: sum over lanes with same hl (l ^ 8,16,32), then fetch denom of head hc
    dsum += __shfl_xor(dsum, 8);
    dsum += __shfl_xor(dsum, 16);
    dsum += __shfl_xor(dsum, 32);
    float denom = __shfl(dsum, hc);       // lane hc has (l&7)==hc
    float inv = 1.f / (denom + 1e-16f);
    float v0 = acc0 * inv; v0 = v0 > 0.f ? v0 : expm1f(v0);
    float v1 = acc1 * inv; v1 = v1 > 0.f ? v1 : expm1f(v1);

    // W1 projection: channels 2l, 2l+1 -> w1[4l .. 4l+3]
    float4 wv = *reinterpret_cast<const float4*>(&w1[l * 4]);
    float r0 = v0 * wv.x + v1 * wv.z;
    float r1 = v0 * wv.y + v1 * wv.w;
#pragma unroll
    for (int off = 32; off > 0; off >>= 1) {
        r0 += __shfl_down(r0, off);
        r1 += __shfl_down(r1, off);
    }
    if (l == 0) {
        float s1v = r0 * asrc1[0] + r1 * asrc1[1];
        float t1v = r0 * atrg1[0] + r1 * atrg1[1];
        float4 pk; pk.x = r0; pk.y = r1; pk.z = s1v; pk.w = 0.f;
        pk1[n] = pk;
        t1[n] = t1v;
    }
}

// ---------------- Layer-1 aggregate + mean + log_softmax -> out ----------------
__global__ __launch_bounds__(256) void node_accum1_kernel(
    const int* __restrict__ rowptr, const int* __restrict__ colsrc,
    const float4* __restrict__ pk1, const float* __restrict__ t1,
    float* __restrict__ out, int n_nodes)
{
    int lane = threadIdx.x & 63;
    int n = blockIdx.x * 4 + (threadIdx.x >> 6);
    if (n >= n_nodes) return;
    int start = rowptr[n], deg = rowptr[n + 1] - start;
    float tn = t1[n];
    float d = 0.f, a0 = 0.f, a1 = 0.f;
    for (int i = lane; i < deg; i += 64) {
        int se = colsrc[start + i];
        float4 q = pk1[se];
        float p = __expf(lrelu02(q.z + tn) - ESHIFT);
        d += p;
        a0 += p * q.x;
        a1 += p * q.y;
    }
#pragma unroll
    for (int off = 32; off > 0; off >>= 1) {
        d  += __shfl_down(d, off);
        a0 += __shfl_down(a0, off);
        a1 += __shfl_down(a1, off);
    }
    if (lane == 0) {
        float inv = 1.f / (d + 1e-16f);
        float x0 = a0 * inv, x1 = a1 * inv;
        float m = fmaxf(x0, x1);
        float lse = m + logf(__expf(x0 - m) + __expf(x1 - m));
        out[n * 2 + 0] = x0 - lse;
        out[n * 2 + 1] = x1 - lse;
    }
}

extern "C" void kernel_launch(void* const* d_in, const int* in_sizes, int n_in,
                              void* d_out, int out_size, void* d_ws, size_t ws_size,
                              hipStream_t stream) {
    const float* stat  = (const float*)d_in[0];
    const float* dyn0  = (const float*)d_in[1];
    const float* dyn1  = (const float*)d_in[2];
    const int*   src   = (const int*)d_in[3];
    const int*   trg   = (const int*)d_in[4];
    const float* w0    = (const float*)d_in[5];
    const float* asrc0 = (const float*)d_in[6];
    const float* atrg0 = (const float*)d_in[7];
    const float* w1    = (const float*)d_in[8];
    const float* asrc1 = (const float*)d_in[9];
    const float* atrg1 = (const float*)d_in[10];
    float* out = (float*)d_out;

    const int N = in_sizes[0] / 64;   // 50000
    const int E = in_sizes[3];        // 800000

    // ---- workspace layout (16B-aligned chunks) ----
    float* ws = (float*)d_ws;
    size_t off = 0;
    __half2* hp0h = (__half2*)(ws + off); off += (size_t)N * 64;  // N*64 half2 = N*64 floats/2*... (64 half2 = 256B = 64 floats? no: 64*4B=256B) -> N*64 4-byte slots
    float* s0  = ws + off; off += (size_t)N * 8;
    float* t0  = ws + off; off += (size_t)N * 8;
    float4* pk1 = (float4*)(ws + off); off += (size_t)N * 4;
    float* t1  = ws + off; off += (size_t)N;
    off = (off + 3) & ~(size_t)3;
    int* iws    = (int*)(ws + off);
    int* rowptr = iws;               // N+1
    int* cursor = iws + (N + 1);     // N
    int* colsrc = iws + (N + 1) + N; // E
    int* deg    = colsrc + E;        // N
    int* bsum   = deg + N;           // <=1024

    const int NB = (N + 255) / 256;

    // CSR build (by target)
    hipMemsetAsync(deg, 0, (size_t)N * sizeof(int), stream);
    count_kernel<<<(E + 255) / 256, 256, 0, stream>>>(trg, deg, E);
    block_sum_kernel<<<NB, 256, 0, stream>>>(deg, bsum, N);
    bsum_scan_kernel<<<1, 1024, 0, stream>>>(bsum, NB);
    scan_write_kernel<<<NB, 256, 0, stream>>>(deg, bsum, rowptr, cursor, N);
    scatter_kernel<<<(E + 255) / 256, 256, 0, stream>>>(src, trg, cursor, colsrc, E);

    // layer 0 projection + scores (w_s 64KB static LDS)
    gemm0_kernel<<<640, 256, 0, stream>>>(
        stat, dyn0, dyn1, w0, asrc0, atrg0, hp0h, s0, t0, N);

    // layer 0 aggregate + ELU + W1 + layer-1 scores (wave per node)
    node_accum0_kernel<<<(N + 3) / 4, 256, 0, stream>>>(
        rowptr, colsrc, s0, t0, hp0h, w1, asrc1, atrg1, pk1, t1, N);

    // layer 1 aggregate + mean + log_softmax
    node_accum1_kernel<<<(N + 3) / 4, 256, 0, stream>>>(
        rowptr, colsrc, pk1, t1, out, N);
}